// Round 15
// baseline (160.860 us; speedup 1.0000x reference)
//
#include <hip/hip_runtime.h>
#include <hip/hip_bf16.h>
#include <math.h>

typedef __hip_bfloat16 bf16;
typedef short bf16x8 __attribute__((ext_vector_type(8)));
typedef float f32x4 __attribute__((ext_vector_type(4)));
typedef unsigned short u16;

#define R_TOT 4096   // B*N
#define NJ 31

// ---- workspace layout (float element offsets) ----
#define OFF_AE   0          // ae as bf16 u16 (4096*256)
#define OFF_QK   1048576    // qk: 4096*10 floats
#define OFF_S1   2097152    // s1: 4096*256 floats
#define OFF_ENT  4542464    // 4096 floats
#define OFF_X    4546560    // x as bf16 u16 (4096*256)
#define OFF_W    5595136    // canonical weights base
// relative to W:
#define W_E1W   0
#define W_E1B   640
#define W_E2P   768        // e2 B-pack: 32768 bf16
#define W_E2B   33536
#define W_H1B   101120
#define W_VWP   101376     // vw B-pack: 8192 bf16
#define W_W1EP  167684     // W1e B-pack: 8192 bf16
#define W_HE2P  171780     // E = he@hm2 B-pack: 4096 bf16
#define W_CB    173828     // cb0, cb1
#define W_S1P   200452     // s1 B-pack: 65536 bf16
#define W_VW    235780
#define W_VB    238340
#define W_DECWT 238596     // dec B-pack: 262144 bf16
#define W_DECB  500740
#define W_QKM   501252     // M = qw^T@kw B-pack: 4096 bf16

// ---- output element offsets ----
#define OUT0 0
#define OUT1 2097152
#define OUT2 2224128
#define OUT3 2351104
#define OUT4 2351105
#define OUT5 2478081

__device__ __forceinline__ float b2f(bf16 x) { return __bfloat162float(x); }
__device__ __forceinline__ float ldin(const void* p, int i, int flag) {
    return flag ? b2f(((const bf16*)p)[i]) : ((const float*)p)[i];
}
__device__ __forceinline__ void stout(void* p, int i, float v, int flag) {
    if (flag) ((bf16*)p)[i] = __float2bfloat16(v);
    else      ((float*)p)[i] = v;
}
__device__ __forceinline__ u16 f2bbits(float v) {
    bf16 h = __float2bfloat16(v);
    return *(u16*)&h;
}
// per-wave inline dtype detect: P(misclassify) = 0.4^64 ~ 0
__device__ __forceinline__ int detect_flag(const void* emb) {
    float x = ((const float*)emb)[threadIdx.x & 63];
    int sane = (x == x) && (fabsf(x) < 1e20f);
    unsigned long long m = __ballot(sane);
    return (__popcll(m) == 64) ? 0 : 1;  // 0=fp32, 1=bf16
}

// ---------------- K0: prep ONLY what k_embed needs (659 blocks) ----------------
__global__ __launch_bounds__(256) void k_prep(
        const void* emb,
        const void* e1w, const void* e1b, const void* e2w, const void* e2b,
        const void* h1w, const void* h1b, const void* qw,  const void* kw,
        const void* vw,  const void* vb,  const void* decb,
        float* W) {
    int flag = detect_flag(emb);
    int blk = blockIdx.x;
    int tid = threadIdx.x;
    if (blk < 384) {
        int p; const void* src; int ldm, Wdst;
        if (blk < 128) { p = blk * 256 + tid;         src = e2w; ldm = 128; Wdst = W_E2P; }
        else           { p = (blk - 128) * 256 + tid; src = h1w; ldm = 263; Wdst = W_S1P; }
        int jj   = p & 7;
        int lane = (p >> 3) & 63;
        int tile = p >> 9;
        int nt = tile & 15, kt = tile >> 4;
        int n = nt * 16 + (lane & 15);
        int k = kt * 32 + ((lane >> 4) << 3) + jj;
        ((u16*)(W + Wdst))[p] = f2bbits(ldin(src, n * ldm + k, flag));
    } else if (blk < 640) {
        // qkm: M[c][n] = sum_d qw[d*256+c]*kw[d*10+n]; 16 lanes per entry
        int p = (blk - 384) * 16 + (tid >> 4);
        int l = tid & 15;
        int jj = p & 7, lane = (p >> 3) & 63, kt = p >> 9;
        int k = kt * 32 + ((lane >> 4) << 3) + jj;
        int n = lane & 15;
        float v = 0.f;
        if (n < 10) {
#pragma unroll
            for (int dd = 0; dd < 16; dd++) {
                int d = l + 16 * dd;
                v += ldin(qw, d * 256 + k, flag) * ldin(kw, d * 10 + n, flag);
            }
        }
        v += __shfl_xor(v, 1, 64); v += __shfl_xor(v, 2, 64);
        v += __shfl_xor(v, 4, 64); v += __shfl_xor(v, 8, 64);
        if (l == 0) ((u16*)(W + W_QKM))[p] = f2bbits(v);
    } else {
        int q2 = (blk - 640) * 256 + tid;
        if      (q2 < 640)   W[W_E1W  + q2]           = ldin(e1w,  q2,          flag);
        else if (q2 < 768)   W[W_E1B  + (q2 - 640)]   = ldin(e1b,  q2 - 640,    flag);
        else if (q2 < 1024)  W[W_E2B  + (q2 - 768)]   = ldin(e2b,  q2 - 768,    flag);
        else if (q2 < 1280)  W[W_H1B  + (q2 - 1024)]  = ldin(h1b,  q2 - 1024,   flag);
        else if (q2 < 3840)  W[W_VW   + (q2 - 1280)]  = ldin(vw,   q2 - 1280,   flag);
        else if (q2 < 4096)  W[W_VB   + (q2 - 3840)]  = ldin(vb,   q2 - 3840,   flag);
        else if (q2 < 4608)  W[W_DECB + (q2 - 4096)]  = ldin(decb, q2 - 4096,   flag);
    }
}

// ---------------- K1: embed MLP + s1 + qk via MFMA (blocks 0..1023: rg x nq)
//                    + concurrent packing (blocks 1024..2368) ----------------
__global__ __launch_bounds__(256) void k_embed(const void* emb, const float* W_,
                                               const void* h1w, const void* h2w, const void* h2b,
                                               const void* hew, const void* heb, const void* decw,
                                               const void* vw,
                                               u16* aeb, float* qkws, float* s1ws) {
    int flag = detect_flag(emb);
    float* W = (float*)W_;
    int blk = blockIdx.x;
    int tid = threadIdx.x;
    if (blk >= 1024) {
        int t = blk - 1024;
        if (t < 1024) {
            // dec B-pack: idx = ((kt*32+nt)*64+lane)*8+jj ; B[k][n] = dec_w[n*512+k]
            int idx = t * 256 + tid;
            int jj   = idx & 7;
            int lane = (idx >> 3) & 63;
            int tile = idx >> 9;
            int nt = tile & 31, kt = tile >> 5;
            int n = nt * 16 + (lane & 15);
            int k = kt * 32 + ((lane >> 4) << 3) + jj;
            ((u16*)(W + W_DECWT))[idx] = f2bbits(ldin(decw, n * 512 + k, flag));
        } else if (t < 1056) {
            int p = (t - 1024) * 256 + tid;
            int jj = p & 7, lane = (p >> 3) & 63, nt = p >> 9;
            int n = nt * 16 + (lane & 15);
            int k = ((lane >> 4) << 3) + jj;
            float v = (k < 7) ? ldin(h1w, n * 263 + 256 + k, flag) : 0.f;
            ((u16*)(W + W_W1EP))[p] = f2bbits(v);
        } else if (t < 1312) {
            int q = (t - 1056) * 16 + (tid >> 4);
            int l = tid & 15;
            int jj = q & 7, lane = (q >> 3) & 63, kt = q >> 9;
            int n = lane & 15;
            int c = kt * 32 + ((lane >> 4) << 3) + jj;
            float v = 0.f;
            if (n < 2) {
#pragma unroll
                for (int dd = 0; dd < 16; dd++) {
                    int d = l + 16 * dd;
                    v += ldin(hew, n * 256 + d, flag) * ldin(h2w, d * 256 + c, flag);
                }
            }
            v += __shfl_xor(v, 1, 64); v += __shfl_xor(v, 2, 64);
            v += __shfl_xor(v, 4, 64); v += __shfl_xor(v, 8, 64);
            if (l == 0) ((u16*)(W + W_HE2P))[q] = f2bbits(v);
        } else if (t == 1312) {
            if (tid < 32) {
                int i = tid >> 4, l = tid & 15;
                float v = 0.f;
#pragma unroll
                for (int dd = 0; dd < 16; dd++) {
                    int d = l + 16 * dd;
                    v += ldin(hew, i * 256 + d, flag) * ldin(h2b, d, flag);
                }
                v += __shfl_xor(v, 1, 64); v += __shfl_xor(v, 2, 64);
                v += __shfl_xor(v, 4, 64); v += __shfl_xor(v, 8, 64);
                if (l == 0) W[W_CB + i] = v + ldin(heb, i, flag);
            }
        } else {
            // vw B-pack: single K-tile (K=32, k<10 real)
            int p = (t - 1313) * 256 + tid;   // < 8192
            int jj = p & 7, lane = (p >> 3) & 63, nt = p >> 9;
            int n = nt * 16 + (lane & 15);
            int k = ((lane >> 4) << 3) + jj;
            float v = (k < 10) ? ldin(vw, n * 10 + k, flag) : 0.f;
            ((u16*)(W + W_VWP))[p] = f2bbits(v);
        }
        return;
    }
    // ---- embed path: rg = blk>>2 (16 rows), nq = blk&3 (s1 col-quarter) ----
    int rg = blk >> 2, nq = blk & 3;
    int r0 = rg * 16;
    __shared__ float embL[16][12];
    __shared__ u16 hB[16][136];
    __shared__ u16 aeB[16][264];
    for (int idx = tid; idx < 16 * 11; idx += 256) {
        int s = idx / 11, t = idx % 11;
        embL[s][t] = ldin(emb, (r0 + s) * 11 + t, flag);
    }
    __syncthreads();
    for (int idx = tid; idx < 16 * 128; idx += 256) {
        int s = idx >> 7, jo = idx & 127;
        float v = W[W_E1B + jo];
#pragma unroll
        for (int t = 0; t < 5; t++) v += W[W_E1W + jo * 5 + t] * embL[s][4 + t];
        hB[s][jo] = f2bbits(v > 0.f ? v : 0.01f * v);
    }
    __syncthreads();
    int wv = tid >> 6, ln = tid & 63;
    int lr = ln & 15, quad = ln >> 4;
    // full ae (redundant across nq; needed as K for s1)
    {
        const bf16x8* Bp = (const bf16x8*)(W + W_E2P);
        f32x4 acc[4];
#pragma unroll
        for (int nt = 0; nt < 4; nt++) acc[nt] = (f32x4){0.f, 0.f, 0.f, 0.f};
#pragma unroll
        for (int kt = 0; kt < 4; kt++) {
            bf16x8 af = *(const bf16x8*)&hB[lr][kt * 32 + (quad << 3)];
#pragma unroll
            for (int nt = 0; nt < 4; nt++) {
                bf16x8 bfr = Bp[(kt * 16 + (wv * 4 + nt)) * 64 + ln];
                acc[nt] = __builtin_amdgcn_mfma_f32_16x16x32_bf16(af, bfr, acc[nt], 0, 0, 0);
            }
        }
#pragma unroll
        for (int nt = 0; nt < 4; nt++) {
            int d = wv * 64 + nt * 16 + lr;
            float bias = W[W_E2B + d];
#pragma unroll
            for (int reg = 0; reg < 4; reg++) {
                int m = quad * 4 + reg;
                float v = acc[nt][reg] + bias;
                v = v > 0.f ? v : 0.01f * v;
                u16 bits = f2bbits(v);
                aeB[m][d] = bits;
                if (nq == 0) aeb[(r0 + m) * 256 + d] = bits;
            }
        }
    }
    __syncthreads();
    // s1 quarter: tile = nq*4 + wv (one 16-col tile per wave)
    {
        const bf16x8* Bs = (const bf16x8*)(W + W_S1P);
        int tile = nq * 4 + wv;
        f32x4 sac = (f32x4){0.f, 0.f, 0.f, 0.f};
#pragma unroll
        for (int kt = 0; kt < 8; kt++) {
            bf16x8 af = *(const bf16x8*)&aeB[lr][kt * 32 + (quad << 3)];
            bf16x8 bs = Bs[(kt * 16 + tile) * 64 + ln];
            sac = __builtin_amdgcn_mfma_f32_16x16x32_bf16(af, bs, sac, 0, 0, 0);
        }
        int d = tile * 16 + lr;
        float bias = W[W_H1B + d];
#pragma unroll
        for (int reg = 0; reg < 4; reg++) {
            int m = quad * 4 + reg;
            s1ws[(r0 + m) * 256 + d] = sac[reg] + bias;
        }
        if (nq == 0 && wv == 0) {
            const bf16x8* Bm = (const bf16x8*)(W + W_QKM);
            f32x4 qk = (f32x4){0.f, 0.f, 0.f, 0.f};
#pragma unroll
            for (int kt = 0; kt < 8; kt++) {
                bf16x8 af = *(const bf16x8*)&aeB[lr][kt * 32 + (quad << 3)];
                qk = __builtin_amdgcn_mfma_f32_16x16x32_bf16(af, Bm[kt * 64 + ln], qk, 0, 0, 0);
            }
            if (lr < 10) {
#pragma unroll
                for (int reg = 0; reg < 4; reg++) {
                    int m = quad * 4 + reg;
                    qkws[(r0 + m) * 10 + lr] = qk[reg];
                }
            }
        }
    }
}

// ---------------- K2: fused kernel, 2 rows per block (grid 2048) ----------------
__global__ __launch_bounds__(256) void k_fused(const void* emb, const void* gum,
                                               const float* s1ws, const float* qkws, const float* W,
                                               u16* xb, float* entws, void* out) {
    int flag = detect_flag(emb);
    int rA = blockIdx.x * 2, rB = rA + 1;
    int b = rA >> 5, i0 = rA & 31;
    __shared__ float embB[32][12];
    __shared__ float seL[2][32][10];
    __shared__ u16 eA[64][40];
    __shared__ u16 a1[64][264];
    __shared__ float pj[4][64][2];
    __shared__ float cL[2][32];
    __shared__ float qkL[2][10];
    int tid = threadIdx.x;
    for (int idx = tid; idx < 32 * 11; idx += 256) {
        int s = idx / 11, t = idx % 11;
        embB[s][t] = ldin(emb, (b * 32 + s) * 11 + t, flag);
    }
    for (int idx = tid; idx < 64 * 40; idx += 256) ((u16*)eA)[idx] = 0;
    if (tid >= 64 && tid < 84) {
        int t = tid - 64;
        qkL[t / 10][t % 10] = qkws[(rA + t / 10) * 10 + (t % 10)];
    }
    __syncthreads();
    // edge features (62 units: row 0/1 x 31 neighbors), algebraic identities
    if (tid < 62) {
        int row = tid / 31, jp = tid - row * 31;
        int i = i0 + row;
        int r = rA + row;
        int j = jp + (jp >= i ? 1 : 0);
        float pix = embB[i][0], piy = embB[i][1], hix = embB[i][2], hiy = embB[i][3];
        float pjx = embB[j][0], pjy = embB[j][1], hjx = embB[j][2], hjy = embB[j][3];
        float ajx = embB[j][7], ajy = embB[j][8];
        float gjx = embB[j][9], gjy = embB[j][10];
        float hn2 = hix * hix + hiy * hiy;
        float csh, snh;
        if (hn2 == 0.f) { csh = 1.f; snh = 0.f; }
        else { float invh = rsqrtf(hn2); csh = hix * invh; snh = hiy * invh; }
        float dx = pjx - pix, dy = pjy - piy;
        float d2 = dx * dx + dy * dy;
        float dist, csd, snd;
        if (d2 == 0.f) { dist = 0.f; csd = 1.f; snd = 0.f; }
        else { float invd = rsqrtf(d2); dist = d2 * invd; csd = dx * invd; snd = dy * invd; }
        float gx = gjx - pix, gy = gjy - piy;
        float g2 = gx * gx + gy * gy;
        float gdist, csg, sng;
        if (g2 == 0.f) { gdist = 0.f; csg = 1.f; sng = 0.f; }
        else { float invg = rsqrtf(g2); gdist = g2 * invg; csg = gx * invg; sng = gy * invg; }
        float f[10];
        f[0] = dist * (1.f / 12.f);
        f[1] = csd * csh + snd * snh;
        f[2] = snd * csh - csd * snh;
        f[3] = hjx; f[4] = hjy; f[5] = ajx; f[6] = ajy;
        f[7] = gdist;
        f[8] = csg * csh + sng * snh;
        f[9] = sng * csh - csg * snh;
#pragma unroll
        for (int t = 0; t < 10; t++) { seL[row][jp][t] = f[t]; eA[row * 32 + jp][t] = f2bbits(f[t]); }
        stout(out, OUT2 + r * NJ + jp, dist, flag);
    }
    __syncthreads();
    int wv = tid >> 6, ln = tid & 63;
    int lr = ln & 15, quad = ln >> 4;
    // A-fragments: m4 0,1 = row A j 0-15/16-31; m4 2,3 = row B
    bf16x8 af[4];
#pragma unroll
    for (int m4 = 0; m4 < 4; m4++) af[m4] = *(const bf16x8*)&eA[m4 * 16 + lr][quad << 3];
    f32x4 vacc[4][4];
    {
        const bf16x8* Bp = (const bf16x8*)(W + W_W1EP);
        const bf16x8* Bv = (const bf16x8*)(W + W_VWP);
#pragma unroll
        for (int nt = 0; nt < 4; nt++) {
            int gnt = wv * 4 + nt;
            int d = gnt * 16 + lr;
            float s1A = s1ws[rA * 256 + d];
            float s1B = s1ws[rB * 256 + d];
            bf16x8 bb = Bp[gnt * 64 + ln];
            bf16x8 bv = Bv[gnt * 64 + ln];
#pragma unroll
            for (int m4 = 0; m4 < 4; m4++) {
                float s1v = (m4 < 2) ? s1A : s1B;
                f32x4 acc = (f32x4){s1v, s1v, s1v, s1v};
                acc = __builtin_amdgcn_mfma_f32_16x16x32_bf16(af[m4], bb, acc, 0, 0, 0);
#pragma unroll
                for (int reg = 0; reg < 4; reg++)
                    a1[m4 * 16 + (quad << 2) + reg][d] = f2bbits(fmaxf(acc[reg], 0.f));
                f32x4 z = (f32x4){0.f, 0.f, 0.f, 0.f};
                vacc[m4][nt] = __builtin_amdgcn_mfma_f32_16x16x32_bf16(af[m4], bv, z, 0, 0, 0);
            }
        }
    }
    __syncthreads();
    // stage B: partial logits = a1 @ E^T (both rows)
    {
        const bf16x8* Ep = (const bf16x8*)(W + W_HE2P);
        f32x4 l[4];
#pragma unroll
        for (int m4 = 0; m4 < 4; m4++) l[m4] = (f32x4){0.f, 0.f, 0.f, 0.f};
#pragma unroll
        for (int kk = 0; kk < 2; kk++) {
            int kt = wv * 2 + kk;
            bf16x8 bb = Ep[kt * 64 + ln];
#pragma unroll
            for (int m4 = 0; m4 < 4; m4++) {
                bf16x8 a = *(const bf16x8*)&a1[m4 * 16 + lr][kt * 32 + (quad << 3)];
                l[m4] = __builtin_amdgcn_mfma_f32_16x16x32_bf16(a, bb, l[m4], 0, 0, 0);
            }
        }
        if (lr < 2) {
#pragma unroll
            for (int m4 = 0; m4 < 4; m4++)
#pragma unroll
                for (int reg = 0; reg < 4; reg++)
                    pj[wv][m4 * 16 + (quad << 2) + reg][lr] = l[m4][reg];
        }
    }
    __syncthreads();
    // stage C: wave 0 -> row A, wave 1 -> row B
    if (wv < 2) {
        int row = wv;
        int r = rA + row;
        if (ln == 31) cL[row][31] = 0.f;
        float hwv = 0.f;
        if (ln < NJ) {
            int mr = row * 32 + ln;
            float p0 = pj[0][mr][0] + pj[1][mr][0] + pj[2][mr][0] + pj[3][mr][0];
            float p1 = pj[0][mr][1] + pj[1][mr][1] + pj[2][mr][1] + pj[3][mr][1];
            float l0 = p0 + W[W_CB + 0], l1 = p1 + W[W_CB + 1];
            float u0 = ldin(gum, (r * NJ + ln) * 2 + 0, flag);
            float u1 = ldin(gum, (r * NJ + ln) * 2 + 1, flag);
            float g0 = -logf(-logf(u0 + 1e-10f) + 1e-10f);
            float g1 = -logf(-logf(u1 + 1e-10f) + 1e-10f);
            float dl = ((l1 + g1) - (l0 + g0)) * 2.0f;  // / tau (=0.5)
            hwv = 1.f / (1.f + expf(-dl));
            stout(out, OUT1 + r * NJ + ln, l1, flag);
            stout(out, OUT4 + r * NJ + ln, hwv, flag);
        }
        float sc = -1e30f;
        if (ln < NJ) {
            float p = 0.f;
#pragma unroll
            for (int t = 0; t < 10; t++) p += qkL[row][t] * seL[row][ln][t];
            sc = p * (1.f / 16.f);
        }
        float m = sc;
#pragma unroll
        for (int s = 32; s >= 1; s >>= 1) m = fmaxf(m, __shfl_xor(m, s, 64));
        float e = (ln < NJ) ? expf(sc - m) : 0.f;
        float sum = e;
#pragma unroll
        for (int s = 32; s >= 1; s >>= 1) sum += __shfl_xor(sum, s, 64);
        float sw = e / sum;
        float cmb = sw * hwv;
        if (ln < NJ) {
            cL[row][ln] = cmb;
            stout(out, OUT5 + r * NJ + ln, cmb, flag);
        }
        float csum = cmb;
#pragma unroll
        for (int s = 32; s >= 1; s >>= 1) csum += __shfl_xor(csum, s, 64);
        float cwn = cmb / (csum + 1e-6f);
        float et = (ln < NJ) ? -cwn * logf(cwn + 1e-6f) : 0.f;
#pragma unroll
        for (int s = 32; s >= 1; s >>= 1) et += __shfl_xor(et, s, 64);
        if (ln == 0) entws[r] = et;
    }
    __syncthreads();
    // stage D: x[d] from V-MFMA accumulators, both rows
    {
        float cj[4][4];
#pragma unroll
        for (int m4 = 0; m4 < 4; m4++) {
            int row = m4 >> 1;
#pragma unroll
            for (int reg = 0; reg < 4; reg++)
                cj[m4][reg] = cL[row][(m4 & 1) * 16 + (quad << 2) + reg];
        }
#pragma unroll
        for (int nt = 0; nt < 4; nt++) {
            int d = (wv * 4 + nt) * 16 + lr;
            float vb = W[W_VB + d];
            float xpA = 0.f, xpB = 0.f;
#pragma unroll
            for (int reg = 0; reg < 4; reg++) {
                xpA += fmaxf(vacc[0][nt][reg] + vb, 0.f) * cj[0][reg];
                xpA += fmaxf(vacc[1][nt][reg] + vb, 0.f) * cj[1][reg];
                xpB += fmaxf(vacc[2][nt][reg] + vb, 0.f) * cj[2][reg];
                xpB += fmaxf(vacc[3][nt][reg] + vb, 0.f) * cj[3][reg];
            }
            xpA += __shfl_xor(xpA, 16, 64);
            xpA += __shfl_xor(xpA, 32, 64);
            xpB += __shfl_xor(xpB, 16, 64);
            xpB += __shfl_xor(xpB, 32, 64);
            if (quad == 0) {
                xb[rA * 256 + d] = f2bbits(xpA);
                xb[rB * 256 + d] = f2bbits(xpB);
            }
        }
    }
}

// ---------------- K3: decoder via MFMA + block-0 entropy epilogue ----------------
__global__ __launch_bounds__(256) void k_dec(const void* emb, const u16* aeb, const u16* xb,
                                             const float* W, const float* entws, void* out) {
    int flag = detect_flag(emb);
    int r0 = (blockIdx.x >> 2) * 32;
    int nq = blockIdx.x & 3;
    __shared__ u16 finB[32][520];
    int tid = threadIdx.x;
    for (int idx = tid; idx < 32 * 512; idx += 256) {
        int s = idx >> 9, c = idx & 511;
        finB[s][c] = (c < 256) ? aeb[(r0 + s) * 256 + c] : xb[(r0 + s) * 256 + (c - 256)];
    }
    __syncthreads();
    int wv = tid >> 6, ln = tid & 63;
    int lr = ln & 15, quad = ln >> 4;
    const bf16x8* Bp = (const bf16x8*)(W + W_DECWT);
    f32x4 acc[2][2];
#pragma unroll
    for (int mt = 0; mt < 2; mt++)
#pragma unroll
        for (int nt = 0; nt < 2; nt++) acc[mt][nt] = (f32x4){0.f, 0.f, 0.f, 0.f};
#pragma unroll
    for (int kt = 0; kt < 16; kt++) {
        bf16x8 af[2];
#pragma unroll
        for (int mt = 0; mt < 2; mt++)
            af[mt] = *(const bf16x8*)&finB[mt * 16 + lr][kt * 32 + (quad << 3)];
#pragma unroll
        for (int nt = 0; nt < 2; nt++) {
            int gnt = nq * 8 + wv * 2 + nt;
            bf16x8 bfr = Bp[(kt * 32 + gnt) * 64 + ln];
#pragma unroll
            for (int mt = 0; mt < 2; mt++)
                acc[mt][nt] = __builtin_amdgcn_mfma_f32_16x16x32_bf16(af[mt], bfr, acc[mt][nt], 0, 0, 0);
        }
    }
#pragma unroll
    for (int nt = 0; nt < 2; nt++) {
        int d = (nq * 8 + wv * 2 + nt) * 16 + lr;
        float bias = W[W_DECB + d];
#pragma unroll
        for (int mt = 0; mt < 2; mt++)
#pragma unroll
            for (int reg = 0; reg < 4; reg++) {
                int m = mt * 16 + quad * 4 + reg;
                stout(out, OUT0 + (r0 + m) * 512 + d, acc[mt][nt][reg] + bias, flag);
            }
    }
    // entropy mean epilogue on block 0
    if (blockIdx.x == 0) {
        __shared__ float red[4];
        float s = 0.f;
        for (int i2 = tid; i2 < R_TOT; i2 += 256) s += entws[i2];
#pragma unroll
        for (int m = 32; m >= 1; m >>= 1) s += __shfl_xor(s, m, 64);
        if ((tid & 63) == 0) red[tid >> 6] = s;
        __syncthreads();
        if (tid == 0) {
            float t = red[0] + red[1] + red[2] + red[3];
            stout(out, OUT3, t / (float)R_TOT, flag);
        }
    }
}

// ---------------- launch ----------------
extern "C" void kernel_launch(void* const* d_in, const int* in_sizes, int n_in,
                              void* d_out, int out_size, void* d_ws, size_t ws_size,
                              hipStream_t stream) {
    const void* emb  = d_in[0];
    const void* gum  = d_in[1];
    const void* e1w  = d_in[2];
    const void* e1b  = d_in[3];
    const void* e2w  = d_in[4];
    const void* e2b  = d_in[5];
    const void* h1w  = d_in[6];
    const void* h1b  = d_in[7];
    const void* h2w  = d_in[8];
    const void* h2b  = d_in[9];
    const void* hew  = d_in[10];
    const void* heb  = d_in[11];
    const void* qw   = d_in[12];
    const void* kw   = d_in[13];
    const void* vw   = d_in[14];
    const void* vb   = d_in[15];
    const void* decw = d_in[16];
    const void* decb = d_in[17];

    float* wsf = (float*)d_ws;
    u16*   aeb  = (u16*)(wsf + OFF_AE);
    float* qkws = wsf + OFF_QK;
    float* s1ws = wsf + OFF_S1;
    float* entw = wsf + OFF_ENT;
    u16*   xb   = (u16*)(wsf + OFF_X);
    float* W    = wsf + OFF_W;

    hipLaunchKernelGGL(k_prep, dim3(659), dim3(256), 0, stream,
                       emb, e1w, e1b, e2w, e2b, h1w, h1b, qw, kw, vw, vb, decb, W);
    hipLaunchKernelGGL(k_embed, dim3(2369), dim3(256), 0, stream,
                       emb, W, h1w, h2w, h2b, hew, heb, decw, vw, aeb, qkws, s1ws);
    hipLaunchKernelGGL(k_fused, dim3(2048), dim3(256), 0, stream,
                       emb, gum, s1ws, qkws, W, xb, entw, d_out);
    hipLaunchKernelGGL(k_dec, dim3(512), dim3(256), 0, stream, emb, aeb, xb, W, entw, d_out);
}

// Round 16
// 152.197 us; speedup vs baseline: 1.0569x; 1.0569x over previous
//
#include <hip/hip_runtime.h>
#include <hip/hip_bf16.h>
#include <math.h>

typedef __hip_bfloat16 bf16;
typedef short bf16x8 __attribute__((ext_vector_type(8)));
typedef float f32x4 __attribute__((ext_vector_type(4)));
typedef unsigned short u16;

#define R_TOT 4096   // B*N
#define NJ 31

// ---- workspace layout (float element offsets) ----
#define OFF_AE   0          // ae as bf16 u16 (4096*256)
#define OFF_QK   1048576    // qk: 4096*10 floats
#define OFF_S1   2097152    // s1: 4096*256 floats
#define OFF_ENT  4542464    // 4096 floats
#define OFF_X    4546560    // x as bf16 u16 (4096*256)
#define OFF_W    5595136    // canonical weights base
// relative to W:
#define W_E1W   0
#define W_E1B   640
#define W_E2P   768        // e2 B-pack: 32768 bf16
#define W_E2B   33536
#define W_H1B   101120
#define W_VWP   101376     // vw B-pack: 8192 bf16
#define W_W1EP  167684     // W1e B-pack: 8192 bf16
#define W_HE2P  171780     // E = he@hm2 B-pack: 4096 bf16
#define W_CB    173828     // cb0, cb1
#define W_S1P   200452     // s1 B-pack: 65536 bf16
#define W_VW    235780
#define W_VB    238340
#define W_DECWT 238596     // dec B-pack: 262144 bf16
#define W_DECB  500740
#define W_QKM   501252     // M = qw^T@kw B-pack: 4096 bf16

// ---- output element offsets ----
#define OUT0 0
#define OUT1 2097152
#define OUT2 2224128
#define OUT3 2351104
#define OUT4 2351105
#define OUT5 2478081

__device__ __forceinline__ float b2f(bf16 x) { return __bfloat162float(x); }
__device__ __forceinline__ float ldin(const void* p, int i, int flag) {
    return flag ? b2f(((const bf16*)p)[i]) : ((const float*)p)[i];
}
__device__ __forceinline__ void stout(void* p, int i, float v, int flag) {
    if (flag) ((bf16*)p)[i] = __float2bfloat16(v);
    else      ((float*)p)[i] = v;
}
__device__ __forceinline__ u16 f2bbits(float v) {
    bf16 h = __float2bfloat16(v);
    return *(u16*)&h;
}
// per-wave inline dtype detect: P(misclassify) = 0.4^64 ~ 0
__device__ __forceinline__ int detect_flag(const void* emb) {
    float x = ((const float*)emb)[threadIdx.x & 63];
    int sane = (x == x) && (fabsf(x) < 1e20f);
    unsigned long long m = __ballot(sane);
    return (__popcll(m) == 64) ? 0 : 1;  // 0=fp32, 1=bf16
}

// ---------------- K0: prep ONLY what k_embed needs (659 blocks) ----------------
__global__ __launch_bounds__(256) void k_prep(
        const void* emb,
        const void* e1w, const void* e1b, const void* e2w, const void* e2b,
        const void* h1w, const void* h1b, const void* qw,  const void* kw,
        const void* vw,  const void* vb,  const void* decb,
        float* W) {
    int flag = detect_flag(emb);
    int blk = blockIdx.x;
    int tid = threadIdx.x;
    if (blk < 384) {
        int p; const void* src; int ldm, Wdst;
        if (blk < 128) { p = blk * 256 + tid;         src = e2w; ldm = 128; Wdst = W_E2P; }
        else           { p = (blk - 128) * 256 + tid; src = h1w; ldm = 263; Wdst = W_S1P; }
        int jj   = p & 7;
        int lane = (p >> 3) & 63;
        int tile = p >> 9;
        int nt = tile & 15, kt = tile >> 4;
        int n = nt * 16 + (lane & 15);
        int k = kt * 32 + ((lane >> 4) << 3) + jj;
        ((u16*)(W + Wdst))[p] = f2bbits(ldin(src, n * ldm + k, flag));
    } else if (blk < 640) {
        // qkm: M[c][n] = sum_d qw[d*256+c]*kw[d*10+n]; 16 lanes per entry
        int p = (blk - 384) * 16 + (tid >> 4);
        int l = tid & 15;
        int jj = p & 7, lane = (p >> 3) & 63, kt = p >> 9;
        int k = kt * 32 + ((lane >> 4) << 3) + jj;
        int n = lane & 15;
        float v = 0.f;
        if (n < 10) {
#pragma unroll
            for (int dd = 0; dd < 16; dd++) {
                int d = l + 16 * dd;
                v += ldin(qw, d * 256 + k, flag) * ldin(kw, d * 10 + n, flag);
            }
        }
        v += __shfl_xor(v, 1, 64); v += __shfl_xor(v, 2, 64);
        v += __shfl_xor(v, 4, 64); v += __shfl_xor(v, 8, 64);
        if (l == 0) ((u16*)(W + W_QKM))[p] = f2bbits(v);
    } else {
        int q2 = (blk - 640) * 256 + tid;
        if      (q2 < 640)   W[W_E1W  + q2]           = ldin(e1w,  q2,          flag);
        else if (q2 < 768)   W[W_E1B  + (q2 - 640)]   = ldin(e1b,  q2 - 640,    flag);
        else if (q2 < 1024)  W[W_E2B  + (q2 - 768)]   = ldin(e2b,  q2 - 768,    flag);
        else if (q2 < 1280)  W[W_H1B  + (q2 - 1024)]  = ldin(h1b,  q2 - 1024,   flag);
        else if (q2 < 3840)  W[W_VW   + (q2 - 1280)]  = ldin(vw,   q2 - 1280,   flag);
        else if (q2 < 4096)  W[W_VB   + (q2 - 3840)]  = ldin(vb,   q2 - 3840,   flag);
        else if (q2 < 4608)  W[W_DECB + (q2 - 4096)]  = ldin(decb, q2 - 4096,   flag);
    }
}

// ---------------- K1: embed MLP + s1 + qk via MFMA (blocks 0..255)
//                    + concurrent packing for later kernels (blocks 256..1600) ----------------
__global__ __launch_bounds__(256) void k_embed(const void* emb, const float* W_,
                                               const void* h1w, const void* h2w, const void* h2b,
                                               const void* hew, const void* heb, const void* decw,
                                               const void* vw,
                                               u16* aeb, float* qkws, float* s1ws) {
    int flag = detect_flag(emb);
    float* W = (float*)W_;
    int blk = blockIdx.x;
    int tid = threadIdx.x;
    if (blk >= 256) {
        if (blk < 1280) {
            int idx = (blk - 256) * 256 + tid;
            int jj   = idx & 7;
            int lane = (idx >> 3) & 63;
            int tile = idx >> 9;
            int nt = tile & 31, kt = tile >> 5;
            int n = nt * 16 + (lane & 15);
            int k = kt * 32 + ((lane >> 4) << 3) + jj;
            ((u16*)(W + W_DECWT))[idx] = f2bbits(ldin(decw, n * 512 + k, flag));
        } else if (blk < 1312) {
            int p = (blk - 1280) * 256 + tid;
            int jj = p & 7, lane = (p >> 3) & 63, nt = p >> 9;
            int n = nt * 16 + (lane & 15);
            int k = ((lane >> 4) << 3) + jj;
            float v = (k < 7) ? ldin(h1w, n * 263 + 256 + k, flag) : 0.f;
            ((u16*)(W + W_W1EP))[p] = f2bbits(v);
        } else if (blk < 1568) {
            int q = (blk - 1312) * 16 + (tid >> 4);
            int l = tid & 15;
            int jj = q & 7, lane = (q >> 3) & 63, kt = q >> 9;
            int n = lane & 15;
            int c = kt * 32 + ((lane >> 4) << 3) + jj;
            float v = 0.f;
            if (n < 2) {
#pragma unroll
                for (int dd = 0; dd < 16; dd++) {
                    int d = l + 16 * dd;
                    v += ldin(hew, n * 256 + d, flag) * ldin(h2w, d * 256 + c, flag);
                }
            }
            v += __shfl_xor(v, 1, 64); v += __shfl_xor(v, 2, 64);
            v += __shfl_xor(v, 4, 64); v += __shfl_xor(v, 8, 64);
            if (l == 0) ((u16*)(W + W_HE2P))[q] = f2bbits(v);
        } else if (blk == 1568) {
            if (tid < 32) {
                int i = tid >> 4, l = tid & 15;
                float v = 0.f;
#pragma unroll
                for (int dd = 0; dd < 16; dd++) {
                    int d = l + 16 * dd;
                    v += ldin(hew, i * 256 + d, flag) * ldin(h2b, d, flag);
                }
                v += __shfl_xor(v, 1, 64); v += __shfl_xor(v, 2, 64);
                v += __shfl_xor(v, 4, 64); v += __shfl_xor(v, 8, 64);
                if (l == 0) W[W_CB + i] = v + ldin(heb, i, flag);
            }
        } else {
            // vw B-pack: single K-tile (K=32, k<10 real): p = (nt*64+lane)*8+jj
            int p = (blk - 1569) * 256 + tid;   // < 8192
            int jj = p & 7, lane = (p >> 3) & 63, nt = p >> 9;
            int n = nt * 16 + (lane & 15);
            int k = ((lane >> 4) << 3) + jj;
            float v = (k < 10) ? ldin(vw, n * 10 + k, flag) : 0.f;
            ((u16*)(W + W_VWP))[p] = f2bbits(v);
        }
        return;
    }
    // ---- embed path (blocks 0..255, 16 rows each) ----
    int r0 = blk * 16;
    __shared__ float embL[16][12];
    __shared__ u16 hB[16][136];
    __shared__ u16 aeB[16][264];
    for (int idx = tid; idx < 16 * 11; idx += 256) {
        int s = idx / 11, t = idx % 11;
        embL[s][t] = ldin(emb, (r0 + s) * 11 + t, flag);
    }
    __syncthreads();
    for (int idx = tid; idx < 16 * 128; idx += 256) {
        int s = idx >> 7, jo = idx & 127;
        float v = W[W_E1B + jo];
#pragma unroll
        for (int t = 0; t < 5; t++) v += W[W_E1W + jo * 5 + t] * embL[s][4 + t];
        hB[s][jo] = f2bbits(v > 0.f ? v : 0.01f * v);
    }
    __syncthreads();
    int wv = tid >> 6, ln = tid & 63;
    int lr = ln & 15, quad = ln >> 4;
    {
        const bf16x8* Bp = (const bf16x8*)(W + W_E2P);
        f32x4 acc[4];
#pragma unroll
        for (int nt = 0; nt < 4; nt++) acc[nt] = (f32x4){0.f, 0.f, 0.f, 0.f};
#pragma unroll
        for (int kt = 0; kt < 4; kt++) {
            bf16x8 af = *(const bf16x8*)&hB[lr][kt * 32 + (quad << 3)];
#pragma unroll
            for (int nt = 0; nt < 4; nt++) {
                bf16x8 bfr = Bp[(kt * 16 + (wv * 4 + nt)) * 64 + ln];
                acc[nt] = __builtin_amdgcn_mfma_f32_16x16x32_bf16(af, bfr, acc[nt], 0, 0, 0);
            }
        }
#pragma unroll
        for (int nt = 0; nt < 4; nt++) {
            int d = wv * 64 + nt * 16 + lr;
            float bias = W[W_E2B + d];
#pragma unroll
            for (int reg = 0; reg < 4; reg++) {
                int m = quad * 4 + reg;
                float v = acc[nt][reg] + bias;
                v = v > 0.f ? v : 0.01f * v;
                u16 bits = f2bbits(v);
                aeB[m][d] = bits;
                aeb[(r0 + m) * 256 + d] = bits;
            }
        }
    }
    __syncthreads();
    {
        const bf16x8* Bs = (const bf16x8*)(W + W_S1P);
        f32x4 sac[4];
#pragma unroll
        for (int nt = 0; nt < 4; nt++) sac[nt] = (f32x4){0.f, 0.f, 0.f, 0.f};
#pragma unroll
        for (int kt = 0; kt < 8; kt++) {
            bf16x8 af = *(const bf16x8*)&aeB[lr][kt * 32 + (quad << 3)];
#pragma unroll
            for (int nt = 0; nt < 4; nt++) {
                bf16x8 bs = Bs[(kt * 16 + (wv * 4 + nt)) * 64 + ln];
                sac[nt] = __builtin_amdgcn_mfma_f32_16x16x32_bf16(af, bs, sac[nt], 0, 0, 0);
            }
        }
#pragma unroll
        for (int nt = 0; nt < 4; nt++) {
            int d = wv * 64 + nt * 16 + lr;
            float bias = W[W_H1B + d];
#pragma unroll
            for (int reg = 0; reg < 4; reg++) {
                int m = quad * 4 + reg;
                s1ws[(r0 + m) * 256 + d] = sac[nt][reg] + bias;
            }
        }
        if (wv == 0) {
            const bf16x8* Bm = (const bf16x8*)(W + W_QKM);
            f32x4 qk = (f32x4){0.f, 0.f, 0.f, 0.f};
#pragma unroll
            for (int kt = 0; kt < 8; kt++) {
                bf16x8 af = *(const bf16x8*)&aeB[lr][kt * 32 + (quad << 3)];
                qk = __builtin_amdgcn_mfma_f32_16x16x32_bf16(af, Bm[kt * 64 + ln], qk, 0, 0, 0);
            }
            if (lr < 10) {
#pragma unroll
                for (int reg = 0; reg < 4; reg++) {
                    int m = quad * 4 + reg;
                    qkws[(r0 + m) * 10 + lr] = qk[reg];
                }
            }
        }
    }
}

// ---------------- K2: fused edges + hard MLP + gumbel + attention + V-MFMA + entropy ----------------
__global__ __launch_bounds__(256) void k_fused(const void* emb, const void* gum,
                                               const float* s1ws, const float* qkws, const float* W,
                                               u16* xb, float* entws, void* out) {
    int flag = detect_flag(emb);
    int r = blockIdx.x;
    int b = r >> 5, i = r & 31;
    __shared__ float embB[32][12];
    __shared__ float seL[32][10];
    __shared__ u16 eA[32][40];      // 10 real features; rows 80 B (16B-aligned, 20-bank stride)
    __shared__ u16 a1[32][264];
    __shared__ float pj[4][32][2];
    __shared__ float cL[32];
    __shared__ float qkL[10];
    int tid = threadIdx.x;
    for (int idx = tid; idx < 32 * 11; idx += 256) {
        int s = idx / 11, t = idx % 11;
        embB[s][t] = ldin(emb, (b * 32 + s) * 11 + t, flag);
    }
    for (int idx = tid; idx < 32 * 40; idx += 256) ((u16*)eA)[idx] = 0;
    if (tid >= 64 && tid < 74) qkL[tid - 64] = qkws[r * 10 + (tid - 64)];
    __syncthreads();
    // edge features via algebraic identities (no atan2/sincos)
    if (tid < NJ) {
        int jp = tid;
        int j = jp + (jp >= i ? 1 : 0);
        float pix = embB[i][0], piy = embB[i][1], hix = embB[i][2], hiy = embB[i][3];
        float pjx = embB[j][0], pjy = embB[j][1], hjx = embB[j][2], hjy = embB[j][3];
        float ajx = embB[j][7], ajy = embB[j][8];
        float gjx = embB[j][9], gjy = embB[j][10];
        float hn2 = hix * hix + hiy * hiy;
        float csh, snh;
        if (hn2 == 0.f) { csh = 1.f; snh = 0.f; }
        else { float invh = rsqrtf(hn2); csh = hix * invh; snh = hiy * invh; }
        float dx = pjx - pix, dy = pjy - piy;
        float d2 = dx * dx + dy * dy;
        float dist, csd, snd;
        if (d2 == 0.f) { dist = 0.f; csd = 1.f; snd = 0.f; }
        else { float invd = rsqrtf(d2); dist = d2 * invd; csd = dx * invd; snd = dy * invd; }
        float gx = gjx - pix, gy = gjy - piy;
        float g2 = gx * gx + gy * gy;
        float gdist, csg, sng;
        if (g2 == 0.f) { gdist = 0.f; csg = 1.f; sng = 0.f; }
        else { float invg = rsqrtf(g2); gdist = g2 * invg; csg = gx * invg; sng = gy * invg; }
        float f[10];
        f[0] = dist * (1.f / 12.f);
        f[1] = csd * csh + snd * snh;      // cos(theta_d - theta_h)
        f[2] = snd * csh - csd * snh;      // sin(theta_d - theta_h)
        f[3] = hjx; f[4] = hjy; f[5] = ajx; f[6] = ajy;
        f[7] = gdist;
        f[8] = csg * csh + sng * snh;
        f[9] = sng * csh - csg * snh;
#pragma unroll
        for (int t = 0; t < 10; t++) { seL[jp][t] = f[t]; eA[jp][t] = f2bbits(f[t]); }
        stout(out, OUT2 + r * NJ + jp, dist, flag);
    }
    __syncthreads();
    int wv = tid >> 6, ln = tid & 63;
    int lr = ln & 15, quad = ln >> 4;
    // A-fragments shared by stage A (W1e: zeros for k>=7) and stage V (vw: zeros for k>=10)
    bf16x8 af0 = *(const bf16x8*)&eA[lr][quad << 3];
    bf16x8 af1 = *(const bf16x8*)&eA[16 + lr][quad << 3];
    f32x4 vacc[2][4];
    {
        const bf16x8* Bp = (const bf16x8*)(W + W_W1EP);
        const bf16x8* Bv = (const bf16x8*)(W + W_VWP);
#pragma unroll
        for (int nt = 0; nt < 4; nt++) {
            int gnt = wv * 4 + nt;
            int d = gnt * 16 + lr;
            float s1v = s1ws[r * 256 + d];
            f32x4 acc0 = (f32x4){s1v, s1v, s1v, s1v};
            f32x4 acc1 = acc0;
            bf16x8 bb = Bp[gnt * 64 + ln];
            acc0 = __builtin_amdgcn_mfma_f32_16x16x32_bf16(af0, bb, acc0, 0, 0, 0);
            acc1 = __builtin_amdgcn_mfma_f32_16x16x32_bf16(af1, bb, acc1, 0, 0, 0);
#pragma unroll
            for (int reg = 0; reg < 4; reg++) {
                a1[(quad << 2) + reg][d]      = f2bbits(fmaxf(acc0[reg], 0.f));
                a1[16 + (quad << 2) + reg][d] = f2bbits(fmaxf(acc1[reg], 0.f));
            }
            // V = edge @ vw^T (bias applied in epilogue)
            bf16x8 bv = Bv[gnt * 64 + ln];
            f32x4 z = (f32x4){0.f, 0.f, 0.f, 0.f};
            vacc[0][nt] = __builtin_amdgcn_mfma_f32_16x16x32_bf16(af0, bv, z, 0, 0, 0);
            vacc[1][nt] = __builtin_amdgcn_mfma_f32_16x16x32_bf16(af1, bv, z, 0, 0, 0);
        }
    }
    __syncthreads();
    // stage B: partial logits = a1 @ E^T
    {
        const bf16x8* Ep = (const bf16x8*)(W + W_HE2P);
        f32x4 l0 = (f32x4){0.f, 0.f, 0.f, 0.f};
        f32x4 l1 = (f32x4){0.f, 0.f, 0.f, 0.f};
#pragma unroll
        for (int kk = 0; kk < 2; kk++) {
            int kt = wv * 2 + kk;
            bf16x8 a0 = *(const bf16x8*)&a1[lr][kt * 32 + (quad << 3)];
            bf16x8 a1f = *(const bf16x8*)&a1[16 + lr][kt * 32 + (quad << 3)];
            bf16x8 bb = Ep[kt * 64 + ln];
            l0 = __builtin_amdgcn_mfma_f32_16x16x32_bf16(a0, bb, l0, 0, 0, 0);
            l1 = __builtin_amdgcn_mfma_f32_16x16x32_bf16(a1f, bb, l1, 0, 0, 0);
        }
        if (lr < 2) {
#pragma unroll
            for (int reg = 0; reg < 4; reg++) {
                pj[wv][(quad << 2) + reg][lr]      = l0[reg];
                pj[wv][16 + (quad << 2) + reg][lr] = l1[reg];
            }
        }
    }
    __syncthreads();
    // stage C (wave 0): gumbel + softmax + combined + entropy
    if (wv == 0) {
        if (ln == 31) cL[31] = 0.f;   // padded j-row for V epilogue
        float hwv = 0.f;
        if (ln < NJ) {
            float p0 = pj[0][ln][0] + pj[1][ln][0] + pj[2][ln][0] + pj[3][ln][0];
            float p1 = pj[0][ln][1] + pj[1][ln][1] + pj[2][ln][1] + pj[3][ln][1];
            float l0 = p0 + W[W_CB + 0], l1 = p1 + W[W_CB + 1];
            float u0 = ldin(gum, (r * NJ + ln) * 2 + 0, flag);
            float u1 = ldin(gum, (r * NJ + ln) * 2 + 1, flag);
            float g0 = -logf(-logf(u0 + 1e-10f) + 1e-10f);
            float g1 = -logf(-logf(u1 + 1e-10f) + 1e-10f);
            float dl = ((l1 + g1) - (l0 + g0)) * 2.0f;  // / tau (=0.5)
            hwv = 1.f / (1.f + expf(-dl));
            stout(out, OUT1 + r * NJ + ln, l1, flag);
            stout(out, OUT4 + r * NJ + ln, hwv, flag);
        }
        float sc = -1e30f;
        if (ln < NJ) {
            float p = 0.f;
#pragma unroll
            for (int t = 0; t < 10; t++) p += qkL[t] * seL[ln][t];
            sc = p * (1.f / 16.f);
        }
        float m = sc;
#pragma unroll
        for (int s = 32; s >= 1; s >>= 1) m = fmaxf(m, __shfl_xor(m, s, 64));
        float e = (ln < NJ) ? expf(sc - m) : 0.f;
        float sum = e;
#pragma unroll
        for (int s = 32; s >= 1; s >>= 1) sum += __shfl_xor(sum, s, 64);
        float sw = e / sum;
        float cmb = sw * hwv;
        if (ln < NJ) {
            cL[ln] = cmb;
            stout(out, OUT5 + r * NJ + ln, cmb, flag);
        }
        float csum = cmb;
#pragma unroll
        for (int s = 32; s >= 1; s >>= 1) csum += __shfl_xor(csum, s, 64);
        float cwn = cmb / (csum + 1e-6f);
        float et = (ln < NJ) ? -cwn * logf(cwn + 1e-6f) : 0.f;
#pragma unroll
        for (int s = 32; s >= 1; s >>= 1) et += __shfl_xor(et, s, 64);
        if (ln == 0) entws[r] = et;
    }
    __syncthreads();
    // stage D: x[d] = sum_j relu(V[j][d] + vb[d]) * combined_j  (from V-MFMA accumulators)
    {
        float cj[2][4];
#pragma unroll
        for (int mt = 0; mt < 2; mt++)
#pragma unroll
            for (int reg = 0; reg < 4; reg++) cj[mt][reg] = cL[mt * 16 + (quad << 2) + reg];
#pragma unroll
        for (int nt = 0; nt < 4; nt++) {
            int d = (wv * 4 + nt) * 16 + lr;
            float vb = W[W_VB + d];
            float xp = 0.f;
#pragma unroll
            for (int mt = 0; mt < 2; mt++)
#pragma unroll
                for (int reg = 0; reg < 4; reg++)
                    xp += fmaxf(vacc[mt][nt][reg] + vb, 0.f) * cj[mt][reg];
            xp += __shfl_xor(xp, 16, 64);
            xp += __shfl_xor(xp, 32, 64);
            if (quad == 0) xb[r * 256 + d] = f2bbits(xp);
        }
    }
}

// ---------------- K3: decoder via MFMA + block-0 entropy epilogue ----------------
__global__ __launch_bounds__(256) void k_dec(const void* emb, const u16* aeb, const u16* xb,
                                             const float* W, const float* entws, void* out) {
    int flag = detect_flag(emb);
    int r0 = (blockIdx.x >> 2) * 32;
    int nq = blockIdx.x & 3;
    __shared__ u16 finB[32][520];
    int tid = threadIdx.x;
    for (int idx = tid; idx < 32 * 512; idx += 256) {
        int s = idx >> 9, c = idx & 511;
        finB[s][c] = (c < 256) ? aeb[(r0 + s) * 256 + c] : xb[(r0 + s) * 256 + (c - 256)];
    }
    __syncthreads();
    int wv = tid >> 6, ln = tid & 63;
    int lr = ln & 15, quad = ln >> 4;
    const bf16x8* Bp = (const bf16x8*)(W + W_DECWT);
    f32x4 acc[2][2];
#pragma unroll
    for (int mt = 0; mt < 2; mt++)
#pragma unroll
        for (int nt = 0; nt < 2; nt++) acc[mt][nt] = (f32x4){0.f, 0.f, 0.f, 0.f};
#pragma unroll
    for (int kt = 0; kt < 16; kt++) {
        bf16x8 af[2];
#pragma unroll
        for (int mt = 0; mt < 2; mt++)
            af[mt] = *(const bf16x8*)&finB[mt * 16 + lr][kt * 32 + (quad << 3)];
#pragma unroll
        for (int nt = 0; nt < 2; nt++) {
            int gnt = nq * 8 + wv * 2 + nt;
            bf16x8 bfr = Bp[(kt * 32 + gnt) * 64 + ln];
#pragma unroll
            for (int mt = 0; mt < 2; mt++)
                acc[mt][nt] = __builtin_amdgcn_mfma_f32_16x16x32_bf16(af[mt], bfr, acc[mt][nt], 0, 0, 0);
        }
    }
#pragma unroll
    for (int nt = 0; nt < 2; nt++) {
        int d = (nq * 8 + wv * 2 + nt) * 16 + lr;
        float bias = W[W_DECB + d];
#pragma unroll
        for (int mt = 0; mt < 2; mt++)
#pragma unroll
            for (int reg = 0; reg < 4; reg++) {
                int m = mt * 16 + quad * 4 + reg;
                stout(out, OUT0 + (r0 + m) * 512 + d, acc[mt][nt][reg] + bias, flag);
            }
    }
    // entropy mean epilogue on block 0 (entws is complete before this kernel starts)
    if (blockIdx.x == 0) {
        __shared__ float red[4];
        float s = 0.f;
        for (int i2 = tid; i2 < R_TOT; i2 += 256) s += entws[i2];
#pragma unroll
        for (int m = 32; m >= 1; m >>= 1) s += __shfl_xor(s, m, 64);
        if ((tid & 63) == 0) red[tid >> 6] = s;
        __syncthreads();
        if (tid == 0) {
            float t = red[0] + red[1] + red[2] + red[3];
            stout(out, OUT3, t / (float)R_TOT, flag);
        }
    }
}

// ---------------- launch ----------------
extern "C" void kernel_launch(void* const* d_in, const int* in_sizes, int n_in,
                              void* d_out, int out_size, void* d_ws, size_t ws_size,
                              hipStream_t stream) {
    const void* emb  = d_in[0];
    const void* gum  = d_in[1];
    const void* e1w  = d_in[2];
    const void* e1b  = d_in[3];
    const void* e2w  = d_in[4];
    const void* e2b  = d_in[5];
    const void* h1w  = d_in[6];
    const void* h1b  = d_in[7];
    const void* h2w  = d_in[8];
    const void* h2b  = d_in[9];
    const void* hew  = d_in[10];
    const void* heb  = d_in[11];
    const void* qw   = d_in[12];
    const void* kw   = d_in[13];
    const void* vw   = d_in[14];
    const void* vb   = d_in[15];
    const void* decw = d_in[16];
    const void* decb = d_in[17];

    float* wsf = (float*)d_ws;
    u16*   aeb  = (u16*)(wsf + OFF_AE);
    float* qkws = wsf + OFF_QK;
    float* s1ws = wsf + OFF_S1;
    float* entw = wsf + OFF_ENT;
    u16*   xb   = (u16*)(wsf + OFF_X);
    float* W    = wsf + OFF_W;

    hipLaunchKernelGGL(k_prep, dim3(659), dim3(256), 0, stream,
                       emb, e1w, e1b, e2w, e2b, h1w, h1b, qw, kw, vw, vb, decb, W);
    hipLaunchKernelGGL(k_embed, dim3(1601), dim3(256), 0, stream,
                       emb, W, h1w, h2w, h2b, hew, heb, decw, vw, aeb, qkws, s1ws);
    hipLaunchKernelGGL(k_fused, dim3(4096), dim3(256), 0, stream,
                       emb, gum, s1ws, qkws, W, xb, entw, d_out);
    hipLaunchKernelGGL(k_dec, dim3(512), dim3(256), 0, stream, emb, aeb, xb, W, entw, d_out);
}